// Round 2
// baseline (19844.202 us; speedup 1.0000x reference)
//
#include <hip/hip_runtime.h>
#include <hip/hip_bf16.h>
#include <math.h>

// ConsciousnessStream: B=32, T=2048, E=1024, S=24
// out = [stream (32*24*1024 f32)] [trace (32*2048*1024 f32)]

typedef __attribute__((ext_vector_type(4))) float f32x4;
typedef __attribute__((ext_vector_type(8))) short bf16x8;

__device__ __forceinline__ ushort f2bf(float f) {
  unsigned int x = __float_as_uint(f);
  x += 0x7fffu + ((x >> 16) & 1u);   // RNE (finite data, no NaN handling)
  return (ushort)(x >> 16);
}
__device__ __forceinline__ float bf2f(ushort u) {
  return __uint_as_float(((unsigned int)u) << 16);
}
__device__ __forceinline__ float sigf(float x) {
  return 1.0f / (1.0f + __expf(-x));
}
__device__ __forceinline__ void gload_lds16(const void* g, void* l) {
  __builtin_amdgcn_global_load_lds(
      (const __attribute__((address_space(1))) unsigned int*)g,
      (__attribute__((address_space(3))) unsigned int*)l, 16, 0, 0);
}

// ---------------------------------------------------------------- converts
__global__ __launch_bounds__(256) void f32_to_bf16_k(const float* __restrict__ in,
                                                     ushort* __restrict__ out, int n) {
  int i = (blockIdx.x * 256 + threadIdx.x) * 8;
  if (i >= n) return;
  float4 a = *(const float4*)(in + i);
  float4 c = *(const float4*)(in + i + 4);
  union { ushort u[8]; uint4 v; } p;
  p.u[0]=f2bf(a.x); p.u[1]=f2bf(a.y); p.u[2]=f2bf(a.z); p.u[3]=f2bf(a.w);
  p.u[4]=f2bf(c.x); p.u[5]=f2bf(c.y); p.u[6]=f2bf(c.z); p.u[7]=f2bf(c.w);
  *(uint4*)(out + i) = p.v;
}

// ------------------------------------------------- bf16 GEMM, Bt = [N][K]
// EPI=0: C = bf16(acc + bias[col]) stored at GI[(t*32+b)*3072+col], m=b*2048+t
// EPI=1: C = bf16(gelu(acc + bias[col])) stored row-major [m][256]
template<int EPI>
__global__ __launch_bounds__(256) void gemm_bt(
    const ushort* __restrict__ A, const ushort* __restrict__ Bt,
    const float* __restrict__ bias, ushort* __restrict__ C,
    int M, int N, int K)
{
  __shared__ ushort lA[128 * 32];
  __shared__ ushort lB[128 * 32];
  const int tid = threadIdx.x;
  const int lane = tid & 63, wid = tid >> 6;
  const int tiles_n = N >> 7;
  const int tm = blockIdx.x / tiles_n, tn = blockIdx.x % tiles_n;
  const int wr = wid >> 1, wc = wid & 1;

  const f32x4 zero = {0.f, 0.f, 0.f, 0.f};
  f32x4 acc[4][4];
#pragma unroll
  for (int i = 0; i < 4; ++i)
#pragma unroll
    for (int n = 0; n < 4; ++n) acc[i][n] = zero;

  const ushort* gA = A + (size_t)tm * 128 * K;
  const ushort* gB = Bt + (size_t)tn * 128 * K;
  const int k0 = (lane >> 4) * 8;

  for (int kt = 0; kt < K; kt += 32) {
    __syncthreads();
#pragma unroll
    for (int i = 0; i < 2; ++i) {
      int chunk = i * 256 + tid;          // 512 16B-chunks per 128x32 tile
      int rr = chunk >> 2, cc = chunk & 3;
      gload_lds16(gA + (size_t)rr * K + kt + cc * 8, lA + chunk * 8);
      gload_lds16(gB + (size_t)rr * K + kt + cc * 8, lB + chunk * 8);
    }
    __syncthreads();
    bf16x8 af[4], bfv[4];
#pragma unroll
    for (int i = 0; i < 4; ++i)
      af[i] = *(const bf16x8*)(lA + (wr * 64 + i * 16 + (lane & 15)) * 32 + k0);
#pragma unroll
    for (int n = 0; n < 4; ++n)
      bfv[n] = *(const bf16x8*)(lB + (wc * 64 + n * 16 + (lane & 15)) * 32 + k0);
#pragma unroll
    for (int i = 0; i < 4; ++i)
#pragma unroll
      for (int n = 0; n < 4; ++n)
        acc[i][n] = __builtin_amdgcn_mfma_f32_16x16x32_bf16(af[i], bfv[n], acc[i][n], 0, 0, 0);
  }

#pragma unroll
  for (int i = 0; i < 4; ++i) {
#pragma unroll
    for (int n = 0; n < 4; ++n) {
#pragma unroll
      for (int j = 0; j < 4; ++j) {
        int m = tm * 128 + wr * 64 + i * 16 + (lane >> 4) * 4 + j;
        int col = tn * 128 + wc * 64 + n * 16 + (lane & 15);
        float v = acc[i][n][j] + bias[col];
        if (EPI == 0) {
          int tt = m & 2047, bb = m >> 11;
          C[(size_t)(tt * 32 + bb) * 3072 + col] = f2bf(v);
        } else {
          float gl = 0.5f * v * (1.0f + erff(v * 0.70710678f));
          C[(size_t)m * 256 + col] = f2bf(gl);
        }
      }
    }
  }
}

// -------------------------------------------- gate reduce: g = sig(GH1.w2+b2)
__global__ __launch_bounds__(256) void gate_reduce(
    const ushort* __restrict__ GH1, const float* __restrict__ w2,
    const float* __restrict__ b2, float* __restrict__ G)
{
  int row = blockIdx.x * 4 + (threadIdx.x >> 6);  // m = b*2048 + t
  int lane = threadIdx.x & 63;
  const ushort* p = GH1 + (size_t)row * 256 + lane * 4;
  ushort4 h4 = *(const ushort4*)p;
  float4 w4 = *(const float4*)(w2 + lane * 4);
  float s = bf2f(h4.x) * w4.x + bf2f(h4.y) * w4.y + bf2f(h4.z) * w4.z + bf2f(h4.w) * w4.w;
#pragma unroll
  for (int o = 32; o > 0; o >>= 1) s += __shfl_down(s, o);
  if (lane == 0) {
    G[(row & 2047) * 32 + (row >> 11)] = sigf(s + b2[0]);
  }
}

// ------------------------------------------------------------------- init
__global__ __launch_bounds__(256) void init_scan(const float* __restrict__ prev,
                                                 ushort* __restrict__ hb,
                                                 int* __restrict__ flags)
{
  int gid = blockIdx.x * 256 + threadIdx.x;   // grid 128*256 = 32768
  if (gid < 32768) {
    int bb = gid >> 10, ee = gid & 1023;
    hb[gid] = f2bf(prev[((size_t)bb * 24 + 23) * 1024 + ee]);  // h0 = prev[:, -1, :]
  }
  if (gid < 2048) flags[gid] = 0;
}

// ------------------------------------------------------- persistent scan
// 64 WGs x 384 threads (6 waves). WG w owns e-slice [w*16, w*16+16).
// LDS: w_hh slice 48x1024 bf16 (96KB, swizzled) + h stage 32x1024 bf16 (64KB).
__global__ __launch_bounds__(384) void scan_kernel(
    const ushort* __restrict__ GI, const float* __restrict__ G,
    const float* __restrict__ w_hh, const float* __restrict__ b_hh,
    ushort* __restrict__ hb, int* __restrict__ flags,
    float* __restrict__ out)
{
  __shared__ ushort wl[48 * 1024];
  __shared__ ushort hl[32 * 1024];
  const int tid = threadIdx.x;
  const int wg = blockIdx.x;
  const int wid = tid >> 6, lane = tid & 63;

  // one-time: w_hh slice -> LDS bf16, XOR-swizzled per 16B unit
  for (int idx = tid; idx < 48 * 128; idx += 384) {
    int r = idx >> 7, c = idx & 127;
    int gate = r >> 4, eo = r & 15;
    const float* src = w_hh + ((size_t)(gate * 1024 + wg * 16 + eo)) * 1024 + c * 8;
    float4 f0 = *(const float4*)src;
    float4 f1 = *(const float4*)(src + 4);
    union { ushort u[8]; uint4 v; } p;
    p.u[0]=f2bf(f0.x); p.u[1]=f2bf(f0.y); p.u[2]=f2bf(f0.z); p.u[3]=f2bf(f0.w);
    p.u[4]=f2bf(f1.x); p.u[5]=f2bf(f1.y); p.u[6]=f2bf(f1.z); p.u[7]=f2bf(f1.w);
    int byte = (r * 2048 + c * 16) ^ ((r & 7) << 4);
    *(uint4*)((char*)wl + byte) = p.v;
  }

  // combine-thread constants (threads 0..255 handle 2 e's each)
  const int b = tid >> 3;
  const int ep = tid & 7;
  const int e2 = wg * 16 + ep * 2;
  float bhr0=0, bhr1=0, bhz0=0, bhz1=0, bhn0=0, bhn1=0;
  float h0r = 0.f, h1r = 0.f;   // own h slice kept in f32 registers
  if (tid < 256) {
    bhr0 = b_hh[e2];        bhr1 = b_hh[e2 + 1];
    bhz0 = b_hh[1024 + e2]; bhz1 = b_hh[1025 + e2];
    bhn0 = b_hh[2048 + e2]; bhn1 = b_hh[2049 + e2];
    unsigned int v = *(const unsigned int*)(hb + (size_t)b * 1024 + e2);
    h0r = bf2f((ushort)(v & 0xffff)); h1r = bf2f((ushort)(v >> 16));
  }

  const int mh = wid & 1, gate = wid >> 1;      // 6 waves: (mh, gate)
  const int arow = mh * 16 + (lane & 15);
  const int brow = gate * 16 + (lane & 15);
  const int k0b = (lane >> 4) * 16;             // byte offset of 8-elem k chunk
  const int abase = arow * 2048, aswz = (arow & 7) << 4;
  const int bbase = brow * 2048, bswz = (brow & 7) << 4;
  const char* hlc = (const char*)hl;
  const char* wlc = (const char*)wl;

  __syncthreads();

  for (int t = 0; t < 2048; ++t) {
    // prefetch x-dependent per-step inputs (hidden under poll+stage+mfma)
    unsigned int gir = 0, giz = 0, gin = 0; float gval = 0.f;
    if (tid < 256) {
      const ushort* gp = GI + ((size_t)t * 32 + b) * 3072 + e2;
      gir = *(const unsigned int*)(gp);
      giz = *(const unsigned int*)(gp + 1024);
      gin = *(const unsigned int*)(gp + 2048);
      gval = G[t * 32 + b];
    }
    // wait for h_t fully published (flag[w] >= t)
    if (wid == 0) {
      for (;;) {
        int f = __hip_atomic_load(flags + lane * 32, __ATOMIC_RELAXED, __HIP_MEMORY_SCOPE_AGENT);
        if (__ballot(f < t) == 0ULL) break;
        __builtin_amdgcn_s_sleep(1);
      }
    }
    __syncthreads();
    __builtin_amdgcn_fence(__ATOMIC_ACQUIRE, "agent");

    // stage h_t bf16 -> LDS, swizzled
    {
      const uint4* hsrc = (const uint4*)(hb + (size_t)(t & 1) * 32768);
      for (int idx = tid; idx < 4096; idx += 384) {
        uint4 v = hsrc[idx];
        int byte = (idx * 16) ^ ((((idx >> 7) & 7)) << 4);
        *(uint4*)((char*)hl + byte) = v;
      }
    }
    __syncthreads();

    // gh tile = h @ w_hh_sliceT, K=1024; two accs for ILP
    f32x4 acc0 = {0.f,0.f,0.f,0.f}, acc1 = {0.f,0.f,0.f,0.f};
#pragma unroll
    for (int kk = 0; kk < 32; kk += 2) {
      int ka = kk * 64 + k0b;
      bf16x8 a0  = *(const bf16x8*)(hlc + abase + ((ka) ^ aswz));
      bf16x8 bv0 = *(const bf16x8*)(wlc + bbase + ((ka) ^ bswz));
      bf16x8 a1  = *(const bf16x8*)(hlc + abase + ((ka + 64) ^ aswz));
      bf16x8 bv1 = *(const bf16x8*)(wlc + bbase + ((ka + 64) ^ bswz));
      acc0 = __builtin_amdgcn_mfma_f32_16x16x32_bf16(a0, bv0, acc0, 0, 0, 0);
      acc1 = __builtin_amdgcn_mfma_f32_16x16x32_bf16(a1, bv1, acc1, 0, 0, 0);
    }
    __syncthreads();

    // exchange gh via LDS overlay (f32 [32][48]) -- hl is free now
    {
      float* ghb = (float*)hl;
      f32x4 accs = acc0 + acc1;
      int col = lane & 15;
#pragma unroll
      for (int j = 0; j < 4; ++j) {
        int bb = mh * 16 + (lane >> 4) * 4 + j;
        ghb[bb * 48 + gate * 16 + col] = accs[j];
      }
    }
    __syncthreads();

    // combine + outputs
    if (tid < 256) {
      const float* ghb = (const float*)hl;
      float hr0v = ghb[b * 48 + ep * 2],      hr1v = ghb[b * 48 + ep * 2 + 1];
      float hz0v = ghb[b * 48 + 16 + ep * 2], hz1v = ghb[b * 48 + 17 + ep * 2];
      float hn0v = ghb[b * 48 + 32 + ep * 2], hn1v = ghb[b * 48 + 33 + ep * 2];
      float r0 = sigf(bf2f((ushort)(gir & 0xffff)) + hr0v + bhr0);
      float r1 = sigf(bf2f((ushort)(gir >> 16))    + hr1v + bhr1);
      float z0 = sigf(bf2f((ushort)(giz & 0xffff)) + hz0v + bhz0);
      float z1 = sigf(bf2f((ushort)(giz >> 16))    + hz1v + bhz1);
      float n0 = tanhf(bf2f((ushort)(gin & 0xffff)) + r0 * (hn0v + bhn0));
      float n1 = tanhf(bf2f((ushort)(gin >> 16))    + r1 * (hn1v + bhn1));
      float nw0 = (1.f - z0) * n0 + z0 * h0r;
      float nw1 = (1.f - z1) * n1 + z1 * h1r;
      float u0 = gval * nw0 + (1.f - gval) * h0r;
      float u1 = gval * nw1 + (1.f - gval) * h1r;
      h0r = u0; h1r = u1;
      float2 uv; uv.x = u0; uv.y = u1;
      *(float2*)(out + 786432 + ((size_t)b * 2048 + t) * 1024 + e2) = uv;   // trace
      if (t >= 2024)
        *(float2*)(out + ((size_t)b * 24 + (t - 2024)) * 1024 + e2) = uv;   // stream
      unsigned int hp = (unsigned int)f2bf(u0) | ((unsigned int)f2bf(u1) << 16);
      __hip_atomic_store((unsigned int*)hb + (size_t)((t + 1) & 1) * 16384 + b * 512 + (e2 >> 1),
                         hp, __ATOMIC_RELAXED, __HIP_MEMORY_SCOPE_AGENT);
    }
    __syncthreads();   // drains all waves' stores (vmcnt) before flag
    if (tid == 0) {
      __builtin_amdgcn_fence(__ATOMIC_RELEASE, "agent");
      __hip_atomic_store(flags + wg * 32, t + 1, __ATOMIC_RELAXED, __HIP_MEMORY_SCOPE_AGENT);
    }
  }
}

// ------------------------------------------------------------------ launch
extern "C" void kernel_launch(void* const* d_in, const int* in_sizes, int n_in,
                              void* d_out, int out_size, void* d_ws, size_t ws_size,
                              hipStream_t stream) {
  const float* x    = (const float*)d_in[0];
  const float* prev = (const float*)d_in[1];
  const float* gw1  = (const float*)d_in[2];
  const float* gb1  = (const float*)d_in[3];
  const float* gw2  = (const float*)d_in[4];
  const float* gb2  = (const float*)d_in[5];
  const float* wih  = (const float*)d_in[6];
  const float* whh  = (const float*)d_in[7];
  const float* bih  = (const float*)d_in[8];
  const float* bhh  = (const float*)d_in[9];
  float* out = (float*)d_out;

  char* ws = (char*)d_ws;
  ushort* xb    = (ushort*)(ws);                       // 134,217,728 B
  ushort* wbih  = (ushort*)(ws + 134217728);           //   6,291,456 B
  ushort* wb1   = (ushort*)(ws + 140509184);           //     524,288 B
  ushort* GI    = (ushort*)(ws + 141033472);           // 402,653,184 B
  ushort* GH1   = (ushort*)(ws + 543686656);           //  33,554,432 B
  float*  Gg    = (float*) (ws + 577241088);           //     262,144 B
  ushort* hb    = (ushort*)(ws + 577503232);           //     131,072 B
  int*    flags = (int*)   (ws + 577634304);           //       8,192 B
  // total 577,642,496 B (~551 MiB) of d_ws

  f32_to_bf16_k<<<32768, 256, 0, stream>>>(x, xb, 67108864);
  f32_to_bf16_k<<<1536, 256, 0, stream>>>(wih, wbih, 3145728);
  f32_to_bf16_k<<<128, 256, 0, stream>>>(gw1, wb1, 262144);
  gemm_bt<0><<<12288, 256, 0, stream>>>(xb, wbih, bih, GI, 65536, 3072, 1024);
  gemm_bt<1><<<1024, 256, 0, stream>>>(xb, wb1, gb1, GH1, 65536, 256, 1024);
  gate_reduce<<<16384, 256, 0, stream>>>(GH1, gw2, gb2, Gg);
  init_scan<<<128, 256, 0, stream>>>(prev, hb, flags);
  scan_kernel<<<64, 384, 0, stream>>>(GI, Gg, whh, bhh, hb, flags, out);
}

// Round 3
// 9657.912 us; speedup vs baseline: 2.0547x; 2.0547x over previous
//
#include <hip/hip_runtime.h>
#include <hip/hip_bf16.h>
#include <math.h>

// ConsciousnessStream: B=32, T=2048, E=1024, S=24
// out = [stream (32*24*1024 f32)] [trace (32*2048*1024 f32)]

typedef __attribute__((ext_vector_type(4))) float f32x4;
typedef __attribute__((ext_vector_type(8))) short bf16x8;

__device__ __forceinline__ ushort f2bf(float f) {
  unsigned int x = __float_as_uint(f);
  x += 0x7fffu + ((x >> 16) & 1u);   // RNE (finite data, no NaN handling)
  return (ushort)(x >> 16);
}
__device__ __forceinline__ float bf2f(ushort u) {
  return __uint_as_float(((unsigned int)u) << 16);
}
__device__ __forceinline__ float sigf(float x) {
  return 1.0f / (1.0f + __expf(-x));
}
__device__ __forceinline__ void gload_lds16(const void* g, void* l) {
  __builtin_amdgcn_global_load_lds(
      (const __attribute__((address_space(1))) unsigned int*)g,
      (__attribute__((address_space(3))) unsigned int*)l, 16, 0, 0);
}

// ---------------------------------------------------------------- converts
__global__ __launch_bounds__(256) void f32_to_bf16_k(const float* __restrict__ in,
                                                     ushort* __restrict__ out, int n) {
  int i = (blockIdx.x * 256 + threadIdx.x) * 8;
  if (i >= n) return;
  float4 a = *(const float4*)(in + i);
  float4 c = *(const float4*)(in + i + 4);
  union { ushort u[8]; uint4 v; } p;
  p.u[0]=f2bf(a.x); p.u[1]=f2bf(a.y); p.u[2]=f2bf(a.z); p.u[3]=f2bf(a.w);
  p.u[4]=f2bf(c.x); p.u[5]=f2bf(c.y); p.u[6]=f2bf(c.z); p.u[7]=f2bf(c.w);
  *(uint4*)(out + i) = p.v;
}

// ------------------------------------------------- bf16 GEMM, Bt = [N][K]
// EPI=0: C = bf16(acc + bias[col]) stored at GI[(t*32+b)*3072+col], m=b*2048+t
// EPI=1: C = bf16(gelu(acc + bias[col])) stored row-major [m][256]
template<int EPI>
__global__ __launch_bounds__(256) void gemm_bt(
    const ushort* __restrict__ A, const ushort* __restrict__ Bt,
    const float* __restrict__ bias, ushort* __restrict__ C,
    int M, int N, int K)
{
  __shared__ ushort lA[128 * 32];
  __shared__ ushort lB[128 * 32];
  const int tid = threadIdx.x;
  const int lane = tid & 63, wid = tid >> 6;
  const int tiles_n = N >> 7;
  const int tm = blockIdx.x / tiles_n, tn = blockIdx.x % tiles_n;
  const int wr = wid >> 1, wc = wid & 1;

  const f32x4 zero = {0.f, 0.f, 0.f, 0.f};
  f32x4 acc[4][4];
#pragma unroll
  for (int i = 0; i < 4; ++i)
#pragma unroll
    for (int n = 0; n < 4; ++n) acc[i][n] = zero;

  const ushort* gA = A + (size_t)tm * 128 * K;
  const ushort* gB = Bt + (size_t)tn * 128 * K;
  const int k0 = (lane >> 4) * 8;

  for (int kt = 0; kt < K; kt += 32) {
    __syncthreads();
#pragma unroll
    for (int i = 0; i < 2; ++i) {
      int chunk = i * 256 + tid;          // 512 16B-chunks per 128x32 tile
      int rr = chunk >> 2, cc = chunk & 3;
      gload_lds16(gA + (size_t)rr * K + kt + cc * 8, lA + chunk * 8);
      gload_lds16(gB + (size_t)rr * K + kt + cc * 8, lB + chunk * 8);
    }
    __syncthreads();
    bf16x8 af[4], bfv[4];
#pragma unroll
    for (int i = 0; i < 4; ++i)
      af[i] = *(const bf16x8*)(lA + (wr * 64 + i * 16 + (lane & 15)) * 32 + k0);
#pragma unroll
    for (int n = 0; n < 4; ++n)
      bfv[n] = *(const bf16x8*)(lB + (wc * 64 + n * 16 + (lane & 15)) * 32 + k0);
#pragma unroll
    for (int i = 0; i < 4; ++i)
#pragma unroll
      for (int n = 0; n < 4; ++n)
        acc[i][n] = __builtin_amdgcn_mfma_f32_16x16x32_bf16(af[i], bfv[n], acc[i][n], 0, 0, 0);
  }

#pragma unroll
  for (int i = 0; i < 4; ++i) {
#pragma unroll
    for (int n = 0; n < 4; ++n) {
#pragma unroll
      for (int j = 0; j < 4; ++j) {
        int m = tm * 128 + wr * 64 + i * 16 + (lane >> 4) * 4 + j;
        int col = tn * 128 + wc * 64 + n * 16 + (lane & 15);
        float v = acc[i][n][j] + bias[col];
        if (EPI == 0) {
          int tt = m & 2047, bb = m >> 11;
          C[(size_t)(tt * 32 + bb) * 3072 + col] = f2bf(v);
        } else {
          float gl = 0.5f * v * (1.0f + erff(v * 0.70710678f));
          C[(size_t)m * 256 + col] = f2bf(gl);
        }
      }
    }
  }
}

// -------------------------------------------- gate reduce: g = sig(GH1.w2+b2)
__global__ __launch_bounds__(256) void gate_reduce(
    const ushort* __restrict__ GH1, const float* __restrict__ w2,
    const float* __restrict__ b2, float* __restrict__ G)
{
  int row = blockIdx.x * 4 + (threadIdx.x >> 6);  // m = b*2048 + t
  int lane = threadIdx.x & 63;
  const ushort* p = GH1 + (size_t)row * 256 + lane * 4;
  ushort4 h4 = *(const ushort4*)p;
  float4 w4 = *(const float4*)(w2 + lane * 4);
  float s = bf2f(h4.x) * w4.x + bf2f(h4.y) * w4.y + bf2f(h4.z) * w4.z + bf2f(h4.w) * w4.w;
#pragma unroll
  for (int o = 32; o > 0; o >>= 1) s += __shfl_down(s, o);
  if (lane == 0) {
    G[(row & 2047) * 32 + (row >> 11)] = sigf(s + b2[0]);
  }
}

// ------------------------------------------------------------------- init
__global__ __launch_bounds__(256) void init_scan(const float* __restrict__ prev,
                                                 ushort* __restrict__ hb,
                                                 int* __restrict__ flags)
{
  int gid = blockIdx.x * 256 + threadIdx.x;   // grid 128*256 = 32768
  if (gid < 32768) {
    int bb = gid >> 10, ee = gid & 1023;
    hb[gid] = f2bf(prev[((size_t)bb * 24 + 23) * 1024 + ee]);  // h0 = prev[:, -1, :]
  }
  if (gid < 2048) flags[gid] = 0;
}

// ------------------------------------------------------- persistent scan
// 64 WGs x 384 threads (6 waves). WG w owns e-slice [w*16, w*16+16).
// LDS: w_hh slice 48x1024 bf16 (96KB, swizzled) + h stage 32x1024 bf16 (64KB).
// No fences: all cross-WG data (hb, flags) moves via relaxed agent-scope
// atomics (sc0 sc1 -> coherence point). __syncthreads' vmcnt(0) drain orders
// h-stores before the flag store.
__global__ __launch_bounds__(384) void scan_kernel(
    const ushort* __restrict__ GI, const float* __restrict__ G,
    const float* __restrict__ w_hh, const float* __restrict__ b_hh,
    ushort* __restrict__ hb, int* __restrict__ flags,
    float* __restrict__ out)
{
  __shared__ ushort wl[48 * 1024];
  __shared__ ushort hl[32 * 1024];
  const int tid = threadIdx.x;
  const int wg = blockIdx.x;
  const int wid = tid >> 6, lane = tid & 63;

  // one-time: w_hh slice -> LDS bf16, XOR-swizzled per 16B unit
  for (int idx = tid; idx < 48 * 128; idx += 384) {
    int r = idx >> 7, c = idx & 127;
    int gate = r >> 4, eo = r & 15;
    const float* src = w_hh + ((size_t)(gate * 1024 + wg * 16 + eo)) * 1024 + c * 8;
    float4 f0 = *(const float4*)src;
    float4 f1 = *(const float4*)(src + 4);
    union { ushort u[8]; uint4 v; } p;
    p.u[0]=f2bf(f0.x); p.u[1]=f2bf(f0.y); p.u[2]=f2bf(f0.z); p.u[3]=f2bf(f0.w);
    p.u[4]=f2bf(f1.x); p.u[5]=f2bf(f1.y); p.u[6]=f2bf(f1.z); p.u[7]=f2bf(f1.w);
    int byte = (r * 2048 + c * 16) ^ ((r & 7) << 4);
    *(uint4*)((char*)wl + byte) = p.v;
  }

  // combine-thread constants (threads 0..255 handle 2 e's each)
  const int b = tid >> 3;
  const int ep = tid & 7;
  const int e2 = wg * 16 + ep * 2;
  float bhr0=0, bhr1=0, bhz0=0, bhz1=0, bhn0=0, bhn1=0;
  float h0r = 0.f, h1r = 0.f;   // own h slice kept in f32 registers
  if (tid < 256) {
    bhr0 = b_hh[e2];        bhr1 = b_hh[e2 + 1];
    bhz0 = b_hh[1024 + e2]; bhz1 = b_hh[1025 + e2];
    bhn0 = b_hh[2048 + e2]; bhn1 = b_hh[2049 + e2];
    unsigned int v = *(const unsigned int*)(hb + (size_t)b * 1024 + e2);
    h0r = bf2f((ushort)(v & 0xffff)); h1r = bf2f((ushort)(v >> 16));
  }

  const int mh = wid & 1, gate = wid >> 1;      // 6 waves: (mh, gate)
  const int arow = mh * 16 + (lane & 15);
  const int brow = gate * 16 + (lane & 15);
  const int k0b = (lane >> 4) * 16;             // byte offset of 8-elem k chunk
  const int abase = arow * 2048, aswz = (arow & 7) << 4;
  const int bbase = brow * 2048, bswz = (brow & 7) << 4;
  const char* hlc = (const char*)hl;
  const char* wlc = (const char*)wl;

  __syncthreads();

  for (int t = 0; t < 2048; ++t) {
    // prefetch x-dependent per-step inputs (hidden under poll+stage+mfma)
    unsigned int gir = 0, giz = 0, gin = 0; float gval = 0.f;
    if (tid < 256) {
      const ushort* gp = GI + ((size_t)t * 32 + b) * 3072 + e2;
      gir = *(const unsigned int*)(gp);
      giz = *(const unsigned int*)(gp + 1024);
      gin = *(const unsigned int*)(gp + 2048);
      gval = G[t * 32 + b];
    }
    // wait for h_t fully published (flag[w] >= t)
    if (wid == 0) {
      for (;;) {
        int f = __hip_atomic_load(flags + lane * 32, __ATOMIC_RELAXED, __HIP_MEMORY_SCOPE_AGENT);
        if (__ballot(f < t) == 0ULL) break;
        __builtin_amdgcn_s_sleep(1);
      }
    }
    __syncthreads();

    // stage h_t bf16 -> LDS, swizzled. 256 threads x 16 16B-chunks, loaded as
    // coherent (agent-scope) 8B atomics, register-buffered so all 32 loads
    // stay in flight; sched_barrier keeps the compiler from fusing the loops.
    if (tid < 256) {
      const unsigned long long* hsrc =
          (const unsigned long long*)(hb + (size_t)(t & 1) * 32768);
      unsigned long long lo[16], hi[16];
#pragma unroll
      for (int i = 0; i < 16; ++i) {
        int idx = tid + i * 256;
        lo[i] = __hip_atomic_load(hsrc + idx * 2,     __ATOMIC_RELAXED, __HIP_MEMORY_SCOPE_AGENT);
        hi[i] = __hip_atomic_load(hsrc + idx * 2 + 1, __ATOMIC_RELAXED, __HIP_MEMORY_SCOPE_AGENT);
      }
      __builtin_amdgcn_sched_barrier(0);
#pragma unroll
      for (int i = 0; i < 16; ++i) {
        int idx = tid + i * 256;
        int byte = (idx * 16) ^ ((((idx >> 7) & 7)) << 4);
        union { unsigned long long q[2]; uint4 v; } u;
        u.q[0] = lo[i]; u.q[1] = hi[i];
        *(uint4*)((char*)hl + byte) = u.v;
      }
    }
    __syncthreads();

    // gh tile = h @ w_hh_sliceT, K=1024; two accs for ILP
    f32x4 acc0 = {0.f,0.f,0.f,0.f}, acc1 = {0.f,0.f,0.f,0.f};
#pragma unroll
    for (int kk = 0; kk < 32; kk += 2) {
      int ka = kk * 64 + k0b;
      bf16x8 a0  = *(const bf16x8*)(hlc + abase + ((ka) ^ aswz));
      bf16x8 bv0 = *(const bf16x8*)(wlc + bbase + ((ka) ^ bswz));
      bf16x8 a1  = *(const bf16x8*)(hlc + abase + ((ka + 64) ^ aswz));
      bf16x8 bv1 = *(const bf16x8*)(wlc + bbase + ((ka + 64) ^ bswz));
      acc0 = __builtin_amdgcn_mfma_f32_16x16x32_bf16(a0, bv0, acc0, 0, 0, 0);
      acc1 = __builtin_amdgcn_mfma_f32_16x16x32_bf16(a1, bv1, acc1, 0, 0, 0);
    }
    __syncthreads();

    // exchange gh via LDS overlay (f32 [32][48]) -- hl is free now
    {
      float* ghb = (float*)hl;
      f32x4 accs = acc0 + acc1;
      int col = lane & 15;
#pragma unroll
      for (int j = 0; j < 4; ++j) {
        int bb = mh * 16 + (lane >> 4) * 4 + j;
        ghb[bb * 48 + gate * 16 + col] = accs[j];
      }
    }
    __syncthreads();

    // combine + outputs
    if (tid < 256) {
      const float* ghb = (const float*)hl;
      float hr0v = ghb[b * 48 + ep * 2],      hr1v = ghb[b * 48 + ep * 2 + 1];
      float hz0v = ghb[b * 48 + 16 + ep * 2], hz1v = ghb[b * 48 + 17 + ep * 2];
      float hn0v = ghb[b * 48 + 32 + ep * 2], hn1v = ghb[b * 48 + 33 + ep * 2];
      float r0 = sigf(bf2f((ushort)(gir & 0xffff)) + hr0v + bhr0);
      float r1 = sigf(bf2f((ushort)(gir >> 16))    + hr1v + bhr1);
      float z0 = sigf(bf2f((ushort)(giz & 0xffff)) + hz0v + bhz0);
      float z1 = sigf(bf2f((ushort)(giz >> 16))    + hz1v + bhz1);
      float n0 = tanhf(bf2f((ushort)(gin & 0xffff)) + r0 * (hn0v + bhn0));
      float n1 = tanhf(bf2f((ushort)(gin >> 16))    + r1 * (hn1v + bhn1));
      float nw0 = (1.f - z0) * n0 + z0 * h0r;
      float nw1 = (1.f - z1) * n1 + z1 * h1r;
      float u0 = gval * nw0 + (1.f - gval) * h0r;
      float u1 = gval * nw1 + (1.f - gval) * h1r;
      h0r = u0; h1r = u1;
      float2 uv; uv.x = u0; uv.y = u1;
      *(float2*)(out + 786432 + ((size_t)b * 2048 + t) * 1024 + e2) = uv;   // trace
      if (t >= 2024)
        *(float2*)(out + ((size_t)b * 24 + (t - 2024)) * 1024 + e2) = uv;   // stream
      unsigned int hp = (unsigned int)f2bf(u0) | ((unsigned int)f2bf(u1) << 16);
      __hip_atomic_store((unsigned int*)hb + (size_t)((t + 1) & 1) * 16384 + b * 512 + (e2 >> 1),
                         hp, __ATOMIC_RELAXED, __HIP_MEMORY_SCOPE_AGENT);
    }
    __syncthreads();   // drains all waves' stores (vmcnt) before flag
    if (tid == 0) {
      __hip_atomic_store(flags + wg * 32, t + 1, __ATOMIC_RELAXED, __HIP_MEMORY_SCOPE_AGENT);
    }
  }
}

// ------------------------------------------------------------------ launch
extern "C" void kernel_launch(void* const* d_in, const int* in_sizes, int n_in,
                              void* d_out, int out_size, void* d_ws, size_t ws_size,
                              hipStream_t stream) {
  const float* x    = (const float*)d_in[0];
  const float* prev = (const float*)d_in[1];
  const float* gw1  = (const float*)d_in[2];
  const float* gb1  = (const float*)d_in[3];
  const float* gw2  = (const float*)d_in[4];
  const float* gb2  = (const float*)d_in[5];
  const float* wih  = (const float*)d_in[6];
  const float* whh  = (const float*)d_in[7];
  const float* bih  = (const float*)d_in[8];
  const float* bhh  = (const float*)d_in[9];
  float* out = (float*)d_out;

  char* ws = (char*)d_ws;
  ushort* xb    = (ushort*)(ws);                       // 134,217,728 B
  ushort* wbih  = (ushort*)(ws + 134217728);           //   6,291,456 B
  ushort* wb1   = (ushort*)(ws + 140509184);           //     524,288 B
  ushort* GI    = (ushort*)(ws + 141033472);           // 402,653,184 B
  ushort* GH1   = (ushort*)(ws + 543686656);           //  33,554,432 B
  float*  Gg    = (float*) (ws + 577241088);           //     262,144 B
  ushort* hb    = (ushort*)(ws + 577503232);           //     131,072 B
  int*    flags = (int*)   (ws + 577634304);           //       8,192 B
  // total 577,642,496 B (~551 MiB) of d_ws

  f32_to_bf16_k<<<32768, 256, 0, stream>>>(x, xb, 67108864);
  f32_to_bf16_k<<<1536, 256, 0, stream>>>(wih, wbih, 3145728);
  f32_to_bf16_k<<<128, 256, 0, stream>>>(gw1, wb1, 262144);
  gemm_bt<0><<<12288, 256, 0, stream>>>(xb, wbih, bih, GI, 65536, 3072, 1024);
  gemm_bt<1><<<1024, 256, 0, stream>>>(xb, wb1, gb1, GH1, 65536, 256, 1024);
  gate_reduce<<<16384, 256, 0, stream>>>(GH1, gw2, gb2, Gg);
  init_scan<<<128, 256, 0, stream>>>(prev, hb, flags);
  scan_kernel<<<64, 384, 0, stream>>>(GI, Gg, whh, bhh, hb, flags, out);
}